// Round 1
// baseline (1633.258 us; speedup 1.0000x reference)
//
#include <hip/hip_runtime.h>

#define N_NODES 100000
#define N_EDGES 1600000
#define HIDDEN 64
#define EDGE_DIM 16
#define N_LAYERS 3
#define N_GRAPHS 512
#define BN_EPS 1e-5f

#define CHUNK 2048
#define NCHUNK ((N_NODES + CHUNK - 1) / CHUNK)   // 49

// ---------------- CSR construction ----------------

__global__ void k_hist(const int* __restrict__ dst, int* __restrict__ hist) {
    int e = blockIdx.x * 256 + threadIdx.x;
    if (e < N_EDGES) atomicAdd(&hist[dst[e]], 1);
}

__global__ void k_scan_partial(const int* __restrict__ hist, int* __restrict__ partial) {
    __shared__ int sd[256];
    int c = blockIdx.x, t = threadIdx.x;
    int base = c * CHUNK + t * 8;
    int s = 0;
#pragma unroll
    for (int u = 0; u < 8; ++u) {
        int i = base + u;
        s += (i < N_NODES) ? hist[i] : 0;
    }
    sd[t] = s;
    __syncthreads();
    for (int d = 128; d > 0; d >>= 1) {
        if (t < d) sd[t] += sd[t + d];
        __syncthreads();
    }
    if (t == 0) partial[c] = sd[0];
}

__global__ void k_scan_base(const int* __restrict__ partial, int* __restrict__ cbase) {
    if (threadIdx.x == 0) {
        int r = 0;
        for (int c = 0; c < NCHUNK; ++c) { cbase[c] = r; r += partial[c]; }
    }
}

__global__ void k_scan_final(const int* __restrict__ hist, const int* __restrict__ cbase,
                             int* __restrict__ row_start, int* __restrict__ cursor) {
    __shared__ int sd[256];
    int c = blockIdx.x, t = threadIdx.x;
    int i0 = c * CHUNK + t * 8;
    int v[8];
    int s = 0;
#pragma unroll
    for (int u = 0; u < 8; ++u) {
        int i = i0 + u;
        v[u] = (i < N_NODES) ? hist[i] : 0;
        s += v[u];
    }
    sd[t] = s;
    __syncthreads();
    for (int d = 1; d < 256; d <<= 1) {
        int x = (t >= d) ? sd[t - d] : 0;
        __syncthreads();
        sd[t] += x;
        __syncthreads();
    }
    int run = cbase[c] + sd[t] - s;  // exclusive prefix for this thread
#pragma unroll
    for (int u = 0; u < 8; ++u) {
        int i = i0 + u;
        if (i <= N_NODES) { row_start[i] = run; cursor[i] = run; }
        run += v[u];
    }
}

__global__ void k_fill(const int* __restrict__ edge_index, int* __restrict__ cursor,
                       int* __restrict__ eid_sorted, int* __restrict__ src_sorted) {
    int e = blockIdx.x * 256 + threadIdx.x;
    if (e >= N_EDGES) return;
    int d = edge_index[N_EDGES + e];
    int p = atomicAdd(&cursor[d], 1);
    eid_sorted[p] = e;
    src_sorted[p] = edge_index[e];
}

// ---------------- per-layer kernels ----------------

// wave-per-node edge aggregation: hin[n][j] = z[n][j] + sum_e relu(z[src][j] + (ea@We+be)[j])
__global__ __launch_bounds__(256) void k_aggregate(
        const float* __restrict__ z, int zstride,
        const float* __restrict__ We, const float* __restrict__ be,
        const int* __restrict__ row_start, const int* __restrict__ eid,
        const int* __restrict__ srcs, const float* __restrict__ ea,
        float* __restrict__ hin) {
    int gid = blockIdx.x * 256 + threadIdx.x;
    int node = gid >> 6;
    int lane = threadIdx.x & 63;
    if (node >= N_NODES) return;
    float w[16];
#pragma unroll
    for (int k = 0; k < 16; ++k) w[k] = We[k * 64 + lane];
    float bl = be[lane];
    int p0 = row_start[node], p1 = row_start[node + 1];
    float acc = 0.f;
    for (int p = p0; p < p1; ++p) {
        int e = eid[p];
        int s = srcs[p];
        const float4* eav = (const float4*)(ea + (size_t)e * 16);
        float4 a0 = eav[0], a1 = eav[1], a2 = eav[2], a3 = eav[3];
        float ev = bl;
        ev = fmaf(a0.x, w[0], ev);  ev = fmaf(a0.y, w[1], ev);
        ev = fmaf(a0.z, w[2], ev);  ev = fmaf(a0.w, w[3], ev);
        ev = fmaf(a1.x, w[4], ev);  ev = fmaf(a1.y, w[5], ev);
        ev = fmaf(a1.z, w[6], ev);  ev = fmaf(a1.w, w[7], ev);
        ev = fmaf(a2.x, w[8], ev);  ev = fmaf(a2.y, w[9], ev);
        ev = fmaf(a2.z, w[10], ev); ev = fmaf(a2.w, w[11], ev);
        ev = fmaf(a3.x, w[12], ev); ev = fmaf(a3.y, w[13], ev);
        ev = fmaf(a3.z, w[14], ev); ev = fmaf(a3.w, w[15], ev);
        float zv = z[(size_t)s * zstride + lane];
        acc += fmaxf(zv + ev, 0.f);
    }
    float zself = z[(size_t)node * zstride + lane];
    hin[(size_t)node * 64 + lane] = zself + acc;
}

// thread-per-node MLP: hout = relu(relu(hin@W1+b1)@W2+b2)
__global__ __launch_bounds__(256) void k_mlp(
        const float* __restrict__ hin,
        const float* __restrict__ W1, const float* __restrict__ b1,
        const float* __restrict__ W2, const float* __restrict__ b2,
        float* __restrict__ hout) {
    int n = blockIdx.x * 256 + threadIdx.x;
    if (n >= N_NODES) return;
    const float4* __restrict__ hv = (const float4*)(hin + (size_t)n * 64);
    float t[64];
#pragma unroll
    for (int j = 0; j < 64; ++j) t[j] = b1[j];
    for (int kc = 0; kc < 16; ++kc) {
        float4 h4 = hv[kc];
        const float* wr = W1 + kc * 4 * 64;
#pragma unroll
        for (int j = 0; j < 64; ++j) t[j] = fmaf(h4.x, wr[j], t[j]);
#pragma unroll
        for (int j = 0; j < 64; ++j) t[j] = fmaf(h4.y, wr[64 + j], t[j]);
#pragma unroll
        for (int j = 0; j < 64; ++j) t[j] = fmaf(h4.z, wr[128 + j], t[j]);
#pragma unroll
        for (int j = 0; j < 64; ++j) t[j] = fmaf(h4.w, wr[192 + j], t[j]);
    }
#pragma unroll
    for (int j = 0; j < 64; ++j) t[j] = fmaxf(t[j], 0.f);
    float o[64];
#pragma unroll
    for (int j = 0; j < 64; ++j) o[j] = b2[j];
#pragma unroll
    for (int k = 0; k < 64; ++k) {
        const float* wr = W2 + k * 64;
        float tk = t[k];
#pragma unroll
        for (int j = 0; j < 64; ++j) o[j] = fmaf(tk, wr[j], o[j]);
    }
    float4* ov = (float4*)(hout + (size_t)n * 64);
#pragma unroll
    for (int i = 0; i < 16; ++i) {
        float4 v;
        v.x = fmaxf(o[4 * i + 0], 0.f);
        v.y = fmaxf(o[4 * i + 1], 0.f);
        v.z = fmaxf(o[4 * i + 2], 0.f);
        v.w = fmaxf(o[4 * i + 3], 0.f);
        ov[i] = v;
    }
}

// per-channel sum / sumsq over all nodes
__global__ __launch_bounds__(256) void k_stats(const float* __restrict__ h,
                                               float* __restrict__ ssum, float* __restrict__ ssq) {
    __shared__ float ls[64], lq[64];
    int tid = blockIdx.x * 256 + threadIdx.x;
    int nth = gridDim.x * 256;
    float4 s = {0, 0, 0, 0}, q = {0, 0, 0, 0};
    const float4* hv = (const float4*)h;
    for (int i = tid; i < N_NODES * 16; i += nth) {
        float4 v = hv[i];
        s.x += v.x; s.y += v.y; s.z += v.z; s.w += v.w;
        q.x += v.x * v.x; q.y += v.y * v.y; q.z += v.z * v.z; q.w += v.w * v.w;
    }
    if (threadIdx.x < 64) { ls[threadIdx.x] = 0.f; lq[threadIdx.x] = 0.f; }
    __syncthreads();
    int j = (threadIdx.x & 15) * 4;
    atomicAdd(&ls[j + 0], s.x); atomicAdd(&ls[j + 1], s.y);
    atomicAdd(&ls[j + 2], s.z); atomicAdd(&ls[j + 3], s.w);
    atomicAdd(&lq[j + 0], q.x); atomicAdd(&lq[j + 1], q.y);
    atomicAdd(&lq[j + 2], q.z); atomicAdd(&lq[j + 3], q.w);
    __syncthreads();
    if (threadIdx.x < 64) {
        atomicAdd(&ssum[threadIdx.x], ls[threadIdx.x]);
        atomicAdd(&ssq[threadIdx.x], lq[threadIdx.x]);
    }
}

__global__ void k_finalize(const float* __restrict__ ssum, const float* __restrict__ ssq,
                           const float* __restrict__ gamma, const float* __restrict__ beta,
                           float* __restrict__ sc, float* __restrict__ sh) {
    int j = threadIdx.x;
    if (j >= 64) return;
    float mean = ssum[j] * (1.f / N_NODES);
    float var = ssq[j] * (1.f / N_NODES) - mean * mean;
    float inv = rsqrtf(var + BN_EPS);
    float scale = gamma[j] * inv;
    sc[j] = scale;
    sh[j] = beta[j] - mean * scale;
}

// normalize and write the zz slice (stride 192)
__global__ __launch_bounds__(256) void k_norm(const float* __restrict__ h,
                                              const float* __restrict__ sc, const float* __restrict__ sh,
                                              float* __restrict__ zzslice) {
    int i = blockIdx.x * 256 + threadIdx.x;  // float4 index, N*16 total
    if (i >= N_NODES * 16) return;
    int n = i >> 4, j4 = i & 15;
    int j = j4 * 4;
    float4 v = ((const float4*)h)[i];
    v.x = fmaf(v.x, sc[j + 0], sh[j + 0]);
    v.y = fmaf(v.y, sc[j + 1], sh[j + 1]);
    v.z = fmaf(v.z, sc[j + 2], sh[j + 2]);
    v.w = fmaf(v.w, sc[j + 3], sh[j + 3]);
    *(float4*)(zzslice + (size_t)n * 192 + j4 * 4) = v;
}

// segment-sum over sorted batch: run-length accumulate, atomic per run
#define GNODES 512
__global__ __launch_bounds__(192) void k_graph(const float* __restrict__ zz,
                                               const int* __restrict__ batch, float* __restrict__ g) {
    int j = threadIdx.x;  // 0..191
    int n0 = blockIdx.x * GNODES;
    int n1 = n0 + GNODES;
    if (n1 > N_NODES) n1 = N_NODES;
    if (n0 >= N_NODES) return;
    float acc = 0.f;
    int cur = batch[n0];
    for (int n = n0; n < n1; ++n) {
        int b = batch[n];
        if (b != cur) {
            atomicAdd(&g[(size_t)cur * 192 + j], acc);
            acc = 0.f;
            cur = b;
        }
        acc += zz[(size_t)n * 192 + j];
    }
    atomicAdd(&g[(size_t)cur * 192 + j], acc);
}

// ---------------- launch ----------------

extern "C" void kernel_launch(void* const* d_in, const int* in_sizes, int n_in,
                              void* d_out, int out_size, void* d_ws, size_t ws_size,
                              hipStream_t stream) {
    const float* x         = (const float*)d_in[0];
    const float* edge_attr = (const float*)d_in[1];
    const float* We        = (const float*)d_in[2];
    const float* be        = (const float*)d_in[3];
    const float* W1        = (const float*)d_in[4];
    const float* b1        = (const float*)d_in[5];
    const float* W2        = (const float*)d_in[6];
    const float* b2        = (const float*)d_in[7];
    const float* gamma     = (const float*)d_in[8];
    const float* beta      = (const float*)d_in[9];
    const int* edge_index  = (const int*)d_in[10];
    const int* batch       = (const int*)d_in[11];

    float* zz = (float*)d_out;
    float* g  = zz + (size_t)N_NODES * 192;

    char* ws = (char*)d_ws;
    size_t off = 0;
    auto alloc = [&](size_t bytes) {
        void* p = ws + off;
        off = (off + bytes + 255) & ~(size_t)255;
        return p;
    };
    int* hist       = (int*)alloc((size_t)N_NODES * 4);
    int* row_start  = (int*)alloc((size_t)(N_NODES + 1) * 4);
    int* cursor     = (int*)alloc((size_t)(N_NODES + 1) * 4);
    int* partial    = (int*)alloc(64 * 4);
    int* cbase      = (int*)alloc(64 * 4);
    int* eid_sorted = (int*)alloc((size_t)N_EDGES * 4);
    int* src_sorted = (int*)alloc((size_t)N_EDGES * 4);
    float* hin      = (float*)alloc((size_t)N_NODES * 64 * 4);
    float* hout     = (float*)alloc((size_t)N_NODES * 64 * 4);
    float* ssum     = (float*)alloc(64 * 4);
    float* ssq      = (float*)alloc(64 * 4);
    float* sc       = (float*)alloc(64 * 4);
    float* sh       = (float*)alloc(64 * 4);

    // CSR build
    hipMemsetAsync(hist, 0, (size_t)N_NODES * 4, stream);
    k_hist<<<(N_EDGES + 255) / 256, 256, 0, stream>>>(edge_index + N_EDGES, hist);
    k_scan_partial<<<NCHUNK, 256, 0, stream>>>(hist, partial);
    k_scan_base<<<1, 64, 0, stream>>>(partial, cbase);
    k_scan_final<<<NCHUNK, 256, 0, stream>>>(hist, cbase, row_start, cursor);
    k_fill<<<(N_EDGES + 255) / 256, 256, 0, stream>>>(edge_index, cursor, eid_sorted, src_sorted);

    hipMemsetAsync(g, 0, (size_t)N_GRAPHS * 192 * 4, stream);

    for (int l = 0; l < N_LAYERS; ++l) {
        const float* zptr = (l == 0) ? x : (zz + (size_t)(l - 1) * 64);
        int zstride = (l == 0) ? 64 : 192;
        k_aggregate<<<(N_NODES * 64 + 255) / 256, 256, 0, stream>>>(
            zptr, zstride, We + (size_t)l * EDGE_DIM * 64, be + (size_t)l * 64,
            row_start, eid_sorted, src_sorted, edge_attr, hin);
        k_mlp<<<(N_NODES + 255) / 256, 256, 0, stream>>>(
            hin, W1 + (size_t)l * 4096, b1 + (size_t)l * 64,
            W2 + (size_t)l * 4096, b2 + (size_t)l * 64, hout);
        hipMemsetAsync(ssum, 0, 64 * 4, stream);
        hipMemsetAsync(ssq, 0, 64 * 4, stream);
        k_stats<<<256, 256, 0, stream>>>(hout, ssum, ssq);
        k_finalize<<<1, 64, 0, stream>>>(ssum, ssq, gamma + (size_t)l * 64, beta + (size_t)l * 64, sc, sh);
        k_norm<<<(N_NODES * 16 + 255) / 256, 256, 0, stream>>>(hout, sc, sh, zz + (size_t)l * 64);
    }
    k_graph<<<(N_NODES + GNODES - 1) / GNODES, 192, 0, stream>>>(zz, batch, g);
}

// Round 2
// 1154.365 us; speedup vs baseline: 1.4149x; 1.4149x over previous
//
#include <hip/hip_runtime.h>

#define N_NODES 100000
#define N_EDGES 1600000
#define HIDDEN 64
#define EDGE_DIM 16
#define N_LAYERS 3
#define N_GRAPHS 512
#define BN_EPS 1e-5f

#define CHUNK 2048
#define NCHUNK ((N_NODES + CHUNK - 1) / CHUNK)   // 49

// ---------------- CSR construction ----------------

__global__ void k_hist(const int* __restrict__ dst, int* __restrict__ hist) {
    int e = blockIdx.x * 256 + threadIdx.x;
    if (e < N_EDGES) atomicAdd(&hist[dst[e]], 1);
}

__global__ void k_scan_partial(const int* __restrict__ hist, int* __restrict__ partial) {
    __shared__ int sd[256];
    int c = blockIdx.x, t = threadIdx.x;
    int base = c * CHUNK + t * 8;
    int s = 0;
#pragma unroll
    for (int u = 0; u < 8; ++u) {
        int i = base + u;
        s += (i < N_NODES) ? hist[i] : 0;
    }
    sd[t] = s;
    __syncthreads();
    for (int d = 128; d > 0; d >>= 1) {
        if (t < d) sd[t] += sd[t + d];
        __syncthreads();
    }
    if (t == 0) partial[c] = sd[0];
}

__global__ void k_scan_base(const int* __restrict__ partial, int* __restrict__ cbase) {
    if (threadIdx.x == 0) {
        int r = 0;
        for (int c = 0; c < NCHUNK; ++c) { cbase[c] = r; r += partial[c]; }
    }
}

__global__ void k_scan_final(const int* __restrict__ hist, const int* __restrict__ cbase,
                             int* __restrict__ row_start, int* __restrict__ cursor) {
    __shared__ int sd[256];
    int c = blockIdx.x, t = threadIdx.x;
    int i0 = c * CHUNK + t * 8;
    int v[8];
    int s = 0;
#pragma unroll
    for (int u = 0; u < 8; ++u) {
        int i = i0 + u;
        v[u] = (i < N_NODES) ? hist[i] : 0;
        s += v[u];
    }
    sd[t] = s;
    __syncthreads();
    for (int d = 1; d < 256; d <<= 1) {
        int x = (t >= d) ? sd[t - d] : 0;
        __syncthreads();
        sd[t] += x;
        __syncthreads();
    }
    int run = cbase[c] + sd[t] - s;  // exclusive prefix for this thread
#pragma unroll
    for (int u = 0; u < 8; ++u) {
        int i = i0 + u;
        if (i <= N_NODES) { row_start[i] = run; cursor[i] = run; }
        run += v[u];
    }
}

// fill CSR; optionally also gather edge_attr rows into dst-sorted order
template<bool GATHER>
__global__ void k_fill(const int* __restrict__ edge_index, int* __restrict__ cursor,
                       int* __restrict__ eid_sorted, int* __restrict__ src_sorted,
                       const float* __restrict__ ea, float* __restrict__ ea_sorted) {
    int e = blockIdx.x * 256 + threadIdx.x;
    if (e >= N_EDGES) return;
    int d = edge_index[N_EDGES + e];
    int p = atomicAdd(&cursor[d], 1);
    src_sorted[p] = edge_index[e];
    if (GATHER) {
        const float4* in = (const float4*)(ea + (size_t)e * 16);
        float4 a0 = in[0], a1 = in[1], a2 = in[2], a3 = in[3];
        float4* out = (float4*)(ea_sorted + (size_t)p * 16);
        out[0] = a0; out[1] = a1; out[2] = a2; out[3] = a3;
    } else {
        eid_sorted[p] = e;
    }
}

// ---------------- per-layer kernels ----------------

// wave-per-node edge aggregation: hin[n][j] = z[n][j] + sum_e relu(z[src][j] + (ea@We+be)[j])
// SORTED: ea already permuted to CSR order (sequential rows). Else go through eid.
template<bool SORTED>
__global__ __launch_bounds__(256) void k_aggregate(
        const float* __restrict__ z, int zstride,
        const float* __restrict__ We, const float* __restrict__ be,
        const int* __restrict__ row_start, const int* __restrict__ eid,
        const int* __restrict__ srcs, const float* __restrict__ ea,
        float* __restrict__ hin) {
    int gid = blockIdx.x * 256 + threadIdx.x;
    // node is wave-uniform; readfirstlane lets the compiler put row_start/srcs/ea
    // loads on the scalar (SMEM) path instead of 64-lane broadcast vector loads.
    int node = __builtin_amdgcn_readfirstlane(gid >> 6);
    int lane = threadIdx.x & 63;
    if (node >= N_NODES) return;
    float w[16];
#pragma unroll
    for (int k = 0; k < 16; ++k) w[k] = We[k * 64 + lane];
    float bl = be[lane];
    int p0 = row_start[node], p1 = row_start[node + 1];
    float acc = 0.f;
    int p = p0;
    // 4-wide unroll: 4 independent z-gathers + 4 ea rows in flight
    for (; p + 4 <= p1; p += 4) {
        int s0 = srcs[p + 0], s1 = srcs[p + 1], s2 = srcs[p + 2], s3 = srcs[p + 3];
        const float* e0 = SORTED ? (ea + (size_t)(p + 0) * 16) : (ea + (size_t)eid[p + 0] * 16);
        const float* e1 = SORTED ? (ea + (size_t)(p + 1) * 16) : (ea + (size_t)eid[p + 1] * 16);
        const float* e2 = SORTED ? (ea + (size_t)(p + 2) * 16) : (ea + (size_t)eid[p + 2] * 16);
        const float* e3 = SORTED ? (ea + (size_t)(p + 3) * 16) : (ea + (size_t)eid[p + 3] * 16);
        float zv0 = z[(size_t)s0 * zstride + lane];
        float zv1 = z[(size_t)s1 * zstride + lane];
        float zv2 = z[(size_t)s2 * zstride + lane];
        float zv3 = z[(size_t)s3 * zstride + lane];
        float ev0 = bl, ev1 = bl, ev2 = bl, ev3 = bl;
#pragma unroll
        for (int k = 0; k < 16; ++k) {
            ev0 = fmaf(e0[k], w[k], ev0);
            ev1 = fmaf(e1[k], w[k], ev1);
            ev2 = fmaf(e2[k], w[k], ev2);
            ev3 = fmaf(e3[k], w[k], ev3);
        }
        acc += fmaxf(zv0 + ev0, 0.f);
        acc += fmaxf(zv1 + ev1, 0.f);
        acc += fmaxf(zv2 + ev2, 0.f);
        acc += fmaxf(zv3 + ev3, 0.f);
    }
    for (; p < p1; ++p) {
        int s = srcs[p];
        const float* er = SORTED ? (ea + (size_t)p * 16) : (ea + (size_t)eid[p] * 16);
        float zv = z[(size_t)s * zstride + lane];
        float ev = bl;
#pragma unroll
        for (int k = 0; k < 16; ++k) ev = fmaf(er[k], w[k], ev);
        acc += fmaxf(zv + ev, 0.f);
    }
    float zself = z[(size_t)node * zstride + lane];
    hin[(size_t)node * 64 + lane] = zself + acc;
}

// thread-per-node MLP: hout = relu(relu(hin@W1+b1)@W2+b2)
__global__ __launch_bounds__(256) void k_mlp(
        const float* __restrict__ hin,
        const float* __restrict__ W1, const float* __restrict__ b1,
        const float* __restrict__ W2, const float* __restrict__ b2,
        float* __restrict__ hout) {
    int n = blockIdx.x * 256 + threadIdx.x;
    if (n >= N_NODES) return;
    const float4* __restrict__ hv = (const float4*)(hin + (size_t)n * 64);
    float t[64];
#pragma unroll
    for (int j = 0; j < 64; ++j) t[j] = b1[j];
    for (int kc = 0; kc < 16; ++kc) {
        float4 h4 = hv[kc];
        const float* wr = W1 + kc * 4 * 64;
#pragma unroll
        for (int j = 0; j < 64; ++j) t[j] = fmaf(h4.x, wr[j], t[j]);
#pragma unroll
        for (int j = 0; j < 64; ++j) t[j] = fmaf(h4.y, wr[64 + j], t[j]);
#pragma unroll
        for (int j = 0; j < 64; ++j) t[j] = fmaf(h4.z, wr[128 + j], t[j]);
#pragma unroll
        for (int j = 0; j < 64; ++j) t[j] = fmaf(h4.w, wr[192 + j], t[j]);
    }
#pragma unroll
    for (int j = 0; j < 64; ++j) t[j] = fmaxf(t[j], 0.f);
    float o[64];
#pragma unroll
    for (int j = 0; j < 64; ++j) o[j] = b2[j];
#pragma unroll
    for (int k = 0; k < 64; ++k) {
        const float* wr = W2 + k * 64;
        float tk = t[k];
#pragma unroll
        for (int j = 0; j < 64; ++j) o[j] = fmaf(tk, wr[j], o[j]);
    }
    float4* ov = (float4*)(hout + (size_t)n * 64);
#pragma unroll
    for (int i = 0; i < 16; ++i) {
        float4 v;
        v.x = fmaxf(o[4 * i + 0], 0.f);
        v.y = fmaxf(o[4 * i + 1], 0.f);
        v.z = fmaxf(o[4 * i + 2], 0.f);
        v.w = fmaxf(o[4 * i + 3], 0.f);
        ov[i] = v;
    }
}

// per-channel sum / sumsq over all nodes
__global__ __launch_bounds__(256) void k_stats(const float* __restrict__ h,
                                               float* __restrict__ ssum, float* __restrict__ ssq) {
    __shared__ float ls[64], lq[64];
    int tid = blockIdx.x * 256 + threadIdx.x;
    int nth = gridDim.x * 256;
    float4 s = {0, 0, 0, 0}, q = {0, 0, 0, 0};
    const float4* hv = (const float4*)h;
    for (int i = tid; i < N_NODES * 16; i += nth) {
        float4 v = hv[i];
        s.x += v.x; s.y += v.y; s.z += v.z; s.w += v.w;
        q.x += v.x * v.x; q.y += v.y * v.y; q.z += v.z * v.z; q.w += v.w * v.w;
    }
    if (threadIdx.x < 64) { ls[threadIdx.x] = 0.f; lq[threadIdx.x] = 0.f; }
    __syncthreads();
    int j = (threadIdx.x & 15) * 4;
    atomicAdd(&ls[j + 0], s.x); atomicAdd(&ls[j + 1], s.y);
    atomicAdd(&ls[j + 2], s.z); atomicAdd(&ls[j + 3], s.w);
    atomicAdd(&lq[j + 0], q.x); atomicAdd(&lq[j + 1], q.y);
    atomicAdd(&lq[j + 2], q.z); atomicAdd(&lq[j + 3], q.w);
    __syncthreads();
    if (threadIdx.x < 64) {
        atomicAdd(&ssum[threadIdx.x], ls[threadIdx.x]);
        atomicAdd(&ssq[threadIdx.x], lq[threadIdx.x]);
    }
}

__global__ void k_finalize(const float* __restrict__ ssum, const float* __restrict__ ssq,
                           const float* __restrict__ gamma, const float* __restrict__ beta,
                           float* __restrict__ sc, float* __restrict__ sh) {
    int j = threadIdx.x;
    if (j >= 64) return;
    float mean = ssum[j] * (1.f / N_NODES);
    float var = ssq[j] * (1.f / N_NODES) - mean * mean;
    float inv = rsqrtf(var + BN_EPS);
    float scale = gamma[j] * inv;
    sc[j] = scale;
    sh[j] = beta[j] - mean * scale;
}

// normalize and write the zz slice (stride 192)
__global__ __launch_bounds__(256) void k_norm(const float* __restrict__ h,
                                              const float* __restrict__ sc, const float* __restrict__ sh,
                                              float* __restrict__ zzslice) {
    int i = blockIdx.x * 256 + threadIdx.x;  // float4 index, N*16 total
    if (i >= N_NODES * 16) return;
    int n = i >> 4, j4 = i & 15;
    int j = j4 * 4;
    float4 v = ((const float4*)h)[i];
    v.x = fmaf(v.x, sc[j + 0], sh[j + 0]);
    v.y = fmaf(v.y, sc[j + 1], sh[j + 1]);
    v.z = fmaf(v.z, sc[j + 2], sh[j + 2]);
    v.w = fmaf(v.w, sc[j + 3], sh[j + 3]);
    *(float4*)(zzslice + (size_t)n * 192 + j4 * 4) = v;
}

// segment-sum over sorted batch: run-length accumulate, atomic per run
#define GNODES 512
__global__ __launch_bounds__(192) void k_graph(const float* __restrict__ zz,
                                               const int* __restrict__ batch, float* __restrict__ g) {
    int j = threadIdx.x;  // 0..191
    int n0 = blockIdx.x * GNODES;
    int n1 = n0 + GNODES;
    if (n1 > N_NODES) n1 = N_NODES;
    if (n0 >= N_NODES) return;
    float acc = 0.f;
    int cur = batch[n0];
    for (int n = n0; n < n1; ++n) {
        int b = batch[n];
        if (b != cur) {
            atomicAdd(&g[(size_t)cur * 192 + j], acc);
            acc = 0.f;
            cur = b;
        }
        acc += zz[(size_t)n * 192 + j];
    }
    atomicAdd(&g[(size_t)cur * 192 + j], acc);
}

// ---------------- launch ----------------

extern "C" void kernel_launch(void* const* d_in, const int* in_sizes, int n_in,
                              void* d_out, int out_size, void* d_ws, size_t ws_size,
                              hipStream_t stream) {
    const float* x         = (const float*)d_in[0];
    const float* edge_attr = (const float*)d_in[1];
    const float* We        = (const float*)d_in[2];
    const float* be        = (const float*)d_in[3];
    const float* W1        = (const float*)d_in[4];
    const float* b1        = (const float*)d_in[5];
    const float* W2        = (const float*)d_in[6];
    const float* b2        = (const float*)d_in[7];
    const float* gamma     = (const float*)d_in[8];
    const float* beta      = (const float*)d_in[9];
    const int* edge_index  = (const int*)d_in[10];
    const int* batch       = (const int*)d_in[11];

    float* zz = (float*)d_out;
    float* g  = zz + (size_t)N_NODES * 192;

    char* ws = (char*)d_ws;
    size_t off = 0;
    auto alloc = [&](size_t bytes) {
        void* p = ws + off;
        off = (off + bytes + 255) & ~(size_t)255;
        return p;
    };
    int* hist       = (int*)alloc((size_t)N_NODES * 4);
    int* row_start  = (int*)alloc((size_t)(N_NODES + 1) * 4);
    int* cursor     = (int*)alloc((size_t)(N_NODES + 1) * 4);
    int* partial    = (int*)alloc(64 * 4);
    int* cbase      = (int*)alloc(64 * 4);
    int* eid_sorted = (int*)alloc((size_t)N_EDGES * 4);
    int* src_sorted = (int*)alloc((size_t)N_EDGES * 4);
    float* hin      = (float*)alloc((size_t)N_NODES * 64 * 4);
    float* hout     = (float*)alloc((size_t)N_NODES * 64 * 4);
    float* ssum     = (float*)alloc(64 * 4);
    float* ssq      = (float*)alloc(64 * 4);
    float* sc       = (float*)alloc(64 * 4);
    float* sh       = (float*)alloc(64 * 4);
    float* ea_sorted = (float*)alloc((size_t)N_EDGES * 16 * 4);   // 102.4 MB, last
    bool use_sorted = (off <= ws_size);   // fixed per run -> graph-capture safe

    // CSR build
    hipMemsetAsync(hist, 0, (size_t)N_NODES * 4, stream);
    k_hist<<<(N_EDGES + 255) / 256, 256, 0, stream>>>(edge_index + N_EDGES, hist);
    k_scan_partial<<<NCHUNK, 256, 0, stream>>>(hist, partial);
    k_scan_base<<<1, 64, 0, stream>>>(partial, cbase);
    k_scan_final<<<NCHUNK, 256, 0, stream>>>(hist, cbase, row_start, cursor);
    if (use_sorted)
        k_fill<true><<<(N_EDGES + 255) / 256, 256, 0, stream>>>(
            edge_index, cursor, eid_sorted, src_sorted, edge_attr, ea_sorted);
    else
        k_fill<false><<<(N_EDGES + 255) / 256, 256, 0, stream>>>(
            edge_index, cursor, eid_sorted, src_sorted, edge_attr, ea_sorted);

    hipMemsetAsync(g, 0, (size_t)N_GRAPHS * 192 * 4, stream);

    for (int l = 0; l < N_LAYERS; ++l) {
        const float* zptr = (l == 0) ? x : (zz + (size_t)(l - 1) * 64);
        int zstride = (l == 0) ? 64 : 192;
        if (use_sorted)
            k_aggregate<true><<<(N_NODES * 64 + 255) / 256, 256, 0, stream>>>(
                zptr, zstride, We + (size_t)l * EDGE_DIM * 64, be + (size_t)l * 64,
                row_start, eid_sorted, src_sorted, ea_sorted, hin);
        else
            k_aggregate<false><<<(N_NODES * 64 + 255) / 256, 256, 0, stream>>>(
                zptr, zstride, We + (size_t)l * EDGE_DIM * 64, be + (size_t)l * 64,
                row_start, eid_sorted, src_sorted, edge_attr, hin);
        k_mlp<<<(N_NODES + 255) / 256, 256, 0, stream>>>(
            hin, W1 + (size_t)l * 4096, b1 + (size_t)l * 64,
            W2 + (size_t)l * 4096, b2 + (size_t)l * 64, hout);
        hipMemsetAsync(ssum, 0, 64 * 4, stream);
        hipMemsetAsync(ssq, 0, 64 * 4, stream);
        k_stats<<<256, 256, 0, stream>>>(hout, ssum, ssq);
        k_finalize<<<1, 64, 0, stream>>>(ssum, ssq, gamma + (size_t)l * 64, beta + (size_t)l * 64, sc, sh);
        k_norm<<<(N_NODES * 16 + 255) / 256, 256, 0, stream>>>(hout, sc, sh, zz + (size_t)l * 64);
    }
    k_graph<<<(N_NODES + GNODES - 1) / GNODES, 192, 0, stream>>>(zz, batch, g);
}

// Round 4
// 1026.159 us; speedup vs baseline: 1.5916x; 1.1249x over previous
//
#include <hip/hip_runtime.h>

#define N_NODES 100000
#define N_EDGES 1600000
#define HIDDEN 64
#define EDGE_DIM 16
#define N_LAYERS 3
#define N_GRAPHS 512
#define BN_EPS 1e-5f

#define CHUNK 2048
#define NCHUNK ((N_NODES + CHUNK - 1) / CHUNK)   // 49

// ---------------- CSR construction ----------------

__global__ void k_hist(const int* __restrict__ dst, int* __restrict__ hist) {
    int e = blockIdx.x * 256 + threadIdx.x;
    if (e < N_EDGES) atomicAdd(&hist[dst[e]], 1);
}

__global__ void k_scan_partial(const int* __restrict__ hist, int* __restrict__ partial) {
    __shared__ int sd[256];
    int c = blockIdx.x, t = threadIdx.x;
    int base = c * CHUNK + t * 8;
    int s = 0;
#pragma unroll
    for (int u = 0; u < 8; ++u) {
        int i = base + u;
        s += (i < N_NODES) ? hist[i] : 0;
    }
    sd[t] = s;
    __syncthreads();
    for (int d = 128; d > 0; d >>= 1) {
        if (t < d) sd[t] += sd[t + d];
        __syncthreads();
    }
    if (t == 0) partial[c] = sd[0];
}

__global__ void k_scan_base(const int* __restrict__ partial, int* __restrict__ cbase) {
    if (threadIdx.x == 0) {
        int r = 0;
        for (int c = 0; c < NCHUNK; ++c) { cbase[c] = r; r += partial[c]; }
    }
}

__global__ void k_scan_final(const int* __restrict__ hist, const int* __restrict__ cbase,
                             int* __restrict__ row_start, int* __restrict__ cursor) {
    __shared__ int sd[256];
    int c = blockIdx.x, t = threadIdx.x;
    int i0 = c * CHUNK + t * 8;
    int v[8];
    int s = 0;
#pragma unroll
    for (int u = 0; u < 8; ++u) {
        int i = i0 + u;
        v[u] = (i < N_NODES) ? hist[i] : 0;
        s += v[u];
    }
    sd[t] = s;
    __syncthreads();
    for (int d = 1; d < 256; d <<= 1) {
        int x = (t >= d) ? sd[t - d] : 0;
        __syncthreads();
        sd[t] += x;
        __syncthreads();
    }
    int run = cbase[c] + sd[t] - s;  // exclusive prefix for this thread
#pragma unroll
    for (int u = 0; u < 8; ++u) {
        int i = i0 + u;
        if (i <= N_NODES) { row_start[i] = run; cursor[i] = run; }
        run += v[u];
    }
}

// fill CSR and gather edge_attr rows into dst-sorted order
__global__ void k_fill(const int* __restrict__ edge_index, int* __restrict__ cursor,
                       int* __restrict__ src_sorted,
                       const float* __restrict__ ea, float* __restrict__ ea_sorted) {
    int e = blockIdx.x * 256 + threadIdx.x;
    if (e >= N_EDGES) return;
    int d = edge_index[N_EDGES + e];
    int p = atomicAdd(&cursor[d], 1);
    src_sorted[p] = edge_index[e];
    const float4* in = (const float4*)(ea + (size_t)e * 16);
    float4 a0 = in[0], a1 = in[1], a2 = in[2], a3 = in[3];
    float4* out = (float4*)(ea_sorted + (size_t)p * 16);
    out[0] = a0; out[1] = a1; out[2] = a2; out[3] = a3;
}

// ---------------- per-layer kernels ----------------

// wave-per-node edge aggregation: hin[n][j] = z[n][j] + sum_e relu(z[src][j] + (ea@We+be)[j])
// ea in CSR-sorted order (row p = position p). 8-wide unroll for latency hiding.
__global__ __launch_bounds__(256) void k_aggregate(
        const float* __restrict__ z, int zstride,
        const float* __restrict__ We, const float* __restrict__ be,
        const int* __restrict__ row_start,
        const int* __restrict__ srcs, const float* __restrict__ ea,
        float* __restrict__ hin) {
    int gid = blockIdx.x * 256 + threadIdx.x;
    int node = __builtin_amdgcn_readfirstlane(gid >> 6);
    int lane = threadIdx.x & 63;
    if (node >= N_NODES) return;
    float w[16];
#pragma unroll
    for (int k = 0; k < 16; ++k) w[k] = We[k * 64 + lane];
    float bl = be[lane];
    int p0 = row_start[node], p1 = row_start[node + 1];
    float acc = 0.f;
    int p = p0;
    // 8 independent z-gathers + 8 ea rows in flight
    for (; p + 8 <= p1; p += 8) {
        int s[8];
        float zv[8], ev[8];
#pragma unroll
        for (int u = 0; u < 8; ++u) s[u] = srcs[p + u];
#pragma unroll
        for (int u = 0; u < 8; ++u) zv[u] = z[(size_t)s[u] * zstride + lane];
#pragma unroll
        for (int u = 0; u < 8; ++u) {
            const float* er = ea + (size_t)(p + u) * 16;
            float e = bl;
#pragma unroll
            for (int k = 0; k < 16; ++k) e = fmaf(er[k], w[k], e);
            ev[u] = e;
        }
#pragma unroll
        for (int u = 0; u < 8; ++u) acc += fmaxf(zv[u] + ev[u], 0.f);
    }
    for (; p + 4 <= p1; p += 4) {
        int s[4];
        float zv[4], ev[4];
#pragma unroll
        for (int u = 0; u < 4; ++u) s[u] = srcs[p + u];
#pragma unroll
        for (int u = 0; u < 4; ++u) zv[u] = z[(size_t)s[u] * zstride + lane];
#pragma unroll
        for (int u = 0; u < 4; ++u) {
            const float* er = ea + (size_t)(p + u) * 16;
            float e = bl;
#pragma unroll
            for (int k = 0; k < 16; ++k) e = fmaf(er[k], w[k], e);
            ev[u] = e;
        }
#pragma unroll
        for (int u = 0; u < 4; ++u) acc += fmaxf(zv[u] + ev[u], 0.f);
    }
    for (; p < p1; ++p) {
        int s = srcs[p];
        const float* er = ea + (size_t)p * 16;
        float zv = z[(size_t)s * zstride + lane];
        float ev = bl;
#pragma unroll
        for (int k = 0; k < 16; ++k) ev = fmaf(er[k], w[k], ev);
        acc += fmaxf(zv + ev, 0.f);
    }
    float zself = z[(size_t)node * zstride + lane];
    hin[(size_t)node * 64 + lane] = zself + acc;
}

// thread-per-node MLP: hout = relu(relu(hin@W1+b1)@W2+b2)
__global__ __launch_bounds__(256) void k_mlp(
        const float* __restrict__ hin,
        const float* __restrict__ W1, const float* __restrict__ b1,
        const float* __restrict__ W2, const float* __restrict__ b2,
        float* __restrict__ hout) {
    int n = blockIdx.x * 256 + threadIdx.x;
    if (n >= N_NODES) return;
    const float4* __restrict__ hv = (const float4*)(hin + (size_t)n * 64);
    float t[64];
#pragma unroll
    for (int j = 0; j < 64; ++j) t[j] = b1[j];
    for (int kc = 0; kc < 16; ++kc) {
        float4 h4 = hv[kc];
        const float* wr = W1 + kc * 4 * 64;
#pragma unroll
        for (int j = 0; j < 64; ++j) t[j] = fmaf(h4.x, wr[j], t[j]);
#pragma unroll
        for (int j = 0; j < 64; ++j) t[j] = fmaf(h4.y, wr[64 + j], t[j]);
#pragma unroll
        for (int j = 0; j < 64; ++j) t[j] = fmaf(h4.z, wr[128 + j], t[j]);
#pragma unroll
        for (int j = 0; j < 64; ++j) t[j] = fmaf(h4.w, wr[192 + j], t[j]);
    }
#pragma unroll
    for (int j = 0; j < 64; ++j) t[j] = fmaxf(t[j], 0.f);
    float o[64];
#pragma unroll
    for (int j = 0; j < 64; ++j) o[j] = b2[j];
#pragma unroll
    for (int k = 0; k < 64; ++k) {
        const float* wr = W2 + k * 64;
        float tk = t[k];
#pragma unroll
        for (int j = 0; j < 64; ++j) o[j] = fmaf(tk, wr[j], o[j]);
    }
    float4* ov = (float4*)(hout + (size_t)n * 64);
#pragma unroll
    for (int i = 0; i < 16; ++i) {
        float4 v;
        v.x = fmaxf(o[4 * i + 0], 0.f);
        v.y = fmaxf(o[4 * i + 1], 0.f);
        v.z = fmaxf(o[4 * i + 2], 0.f);
        v.w = fmaxf(o[4 * i + 3], 0.f);
        ov[i] = v;
    }
}

// per-channel sum / sumsq over all nodes
__global__ __launch_bounds__(256) void k_stats(const float* __restrict__ h,
                                               float* __restrict__ ssum, float* __restrict__ ssq) {
    __shared__ float ls[64], lq[64];
    int tid = blockIdx.x * 256 + threadIdx.x;
    int nth = gridDim.x * 256;
    float4 s = {0, 0, 0, 0}, q = {0, 0, 0, 0};
    const float4* hv = (const float4*)h;
    for (int i = tid; i < N_NODES * 16; i += nth) {
        float4 v = hv[i];
        s.x += v.x; s.y += v.y; s.z += v.z; s.w += v.w;
        q.x += v.x * v.x; q.y += v.y * v.y; q.z += v.z * v.z; q.w += v.w * v.w;
    }
    if (threadIdx.x < 64) { ls[threadIdx.x] = 0.f; lq[threadIdx.x] = 0.f; }
    __syncthreads();
    int j = (threadIdx.x & 15) * 4;
    atomicAdd(&ls[j + 0], s.x); atomicAdd(&ls[j + 1], s.y);
    atomicAdd(&ls[j + 2], s.z); atomicAdd(&ls[j + 3], s.w);
    atomicAdd(&lq[j + 0], q.x); atomicAdd(&lq[j + 1], q.y);
    atomicAdd(&lq[j + 2], q.z); atomicAdd(&lq[j + 3], q.w);
    __syncthreads();
    if (threadIdx.x < 64) {
        atomicAdd(&ssum[threadIdx.x], ls[threadIdx.x]);
        atomicAdd(&ssq[threadIdx.x], lq[threadIdx.x]);
    }
}

__global__ void k_finalize(const float* __restrict__ ssum, const float* __restrict__ ssq,
                           const float* __restrict__ gamma, const float* __restrict__ beta,
                           float* __restrict__ sc, float* __restrict__ sh) {
    int j = threadIdx.x;
    if (j >= 64) return;
    float mean = ssum[j] * (1.f / N_NODES);
    float var = ssq[j] * (1.f / N_NODES) - mean * mean;
    float inv = rsqrtf(var + BN_EPS);
    float scale = gamma[j] * inv;
    sc[j] = scale;
    sh[j] = beta[j] - mean * scale;
}

// normalize and write the zz slice (stride 192)
__global__ __launch_bounds__(256) void k_norm(const float* __restrict__ h,
                                              const float* __restrict__ sc, const float* __restrict__ sh,
                                              float* __restrict__ zzslice) {
    int i = blockIdx.x * 256 + threadIdx.x;  // float4 index, N*16 total
    if (i >= N_NODES * 16) return;
    int n = i >> 4, j4 = i & 15;
    int j = j4 * 4;
    float4 v = ((const float4*)h)[i];
    v.x = fmaf(v.x, sc[j + 0], sh[j + 0]);
    v.y = fmaf(v.y, sc[j + 1], sh[j + 1]);
    v.z = fmaf(v.z, sc[j + 2], sh[j + 2]);
    v.w = fmaf(v.w, sc[j + 3], sh[j + 3]);
    *(float4*)(zzslice + (size_t)n * 192 + j4 * 4) = v;
}

// segment-sum over sorted batch: run-length accumulate, atomic per run.
// GNODES=64 -> 1563 blocks: parallelism first, atomics are cheap (~600K adds).
#define GNODES 64
__global__ __launch_bounds__(192) void k_graph(const float* __restrict__ zz,
                                               const int* __restrict__ batch, float* __restrict__ g) {
    int j = threadIdx.x;  // 0..191; 192 floats = exactly one 768B row -> coalesced
    int n0 = blockIdx.x * GNODES;
    int n1 = n0 + GNODES;
    if (n1 > N_NODES) n1 = N_NODES;
    if (n0 >= N_NODES) return;
    float acc = 0.f;
    int cur = batch[n0];
    for (int n = n0; n < n1; ++n) {
        int b = batch[n];
        if (b != cur) {
            atomicAdd(&g[(size_t)cur * 192 + j], acc);
            acc = 0.f;
            cur = b;
        }
        acc += zz[(size_t)n * 192 + j];
    }
    atomicAdd(&g[(size_t)cur * 192 + j], acc);
}

// ---------------- launch ----------------

extern "C" void kernel_launch(void* const* d_in, const int* in_sizes, int n_in,
                              void* d_out, int out_size, void* d_ws, size_t ws_size,
                              hipStream_t stream) {
    const float* x         = (const float*)d_in[0];
    const float* edge_attr = (const float*)d_in[1];
    const float* We        = (const float*)d_in[2];
    const float* be        = (const float*)d_in[3];
    const float* W1        = (const float*)d_in[4];
    const float* b1        = (const float*)d_in[5];
    const float* W2        = (const float*)d_in[6];
    const float* b2        = (const float*)d_in[7];
    const float* gamma     = (const float*)d_in[8];
    const float* beta      = (const float*)d_in[9];
    const int* edge_index  = (const int*)d_in[10];
    const int* batch       = (const int*)d_in[11];

    float* zz = (float*)d_out;
    float* g  = zz + (size_t)N_NODES * 192;

    char* ws = (char*)d_ws;
    size_t off = 0;
    auto alloc = [&](size_t bytes) {
        void* p = ws + off;
        off = (off + bytes + 255) & ~(size_t)255;
        return p;
    };
    int* hist       = (int*)alloc((size_t)N_NODES * 4);
    int* row_start  = (int*)alloc((size_t)(N_NODES + 1) * 4);
    int* cursor     = (int*)alloc((size_t)(N_NODES + 1) * 4);
    int* partial    = (int*)alloc(64 * 4);
    int* cbase      = (int*)alloc(64 * 4);
    int* src_sorted = (int*)alloc((size_t)N_EDGES * 4);
    float* hin      = (float*)alloc((size_t)N_NODES * 64 * 4);
    float* hout     = (float*)alloc((size_t)N_NODES * 64 * 4);
    float* ssum     = (float*)alloc(64 * 4);
    float* ssq      = (float*)alloc(64 * 4);
    float* sc       = (float*)alloc(64 * 4);
    float* sh       = (float*)alloc(64 * 4);
    float* ea_sorted = (float*)alloc((size_t)N_EDGES * 16 * 4);   // 102.4 MB

    // CSR build
    hipMemsetAsync(hist, 0, (size_t)N_NODES * 4, stream);
    k_hist<<<(N_EDGES + 255) / 256, 256, 0, stream>>>(edge_index + N_EDGES, hist);
    k_scan_partial<<<NCHUNK, 256, 0, stream>>>(hist, partial);
    k_scan_base<<<1, 64, 0, stream>>>(partial, cbase);
    k_scan_final<<<NCHUNK, 256, 0, stream>>>(hist, cbase, row_start, cursor);
    k_fill<<<(N_EDGES + 255) / 256, 256, 0, stream>>>(
        edge_index, cursor, src_sorted, edge_attr, ea_sorted);

    hipMemsetAsync(g, 0, (size_t)N_GRAPHS * 192 * 4, stream);

    for (int l = 0; l < N_LAYERS; ++l) {
        const float* zptr = (l == 0) ? x : (zz + (size_t)(l - 1) * 64);
        int zstride = (l == 0) ? 64 : 192;
        k_aggregate<<<(N_NODES * 64 + 255) / 256, 256, 0, stream>>>(
            zptr, zstride, We + (size_t)l * EDGE_DIM * 64, be + (size_t)l * 64,
            row_start, src_sorted, ea_sorted, hin);
        k_mlp<<<(N_NODES + 255) / 256, 256, 0, stream>>>(
            hin, W1 + (size_t)l * 4096, b1 + (size_t)l * 64,
            W2 + (size_t)l * 4096, b2 + (size_t)l * 64, hout);
        hipMemsetAsync(ssum, 0, 64 * 4, stream);
        hipMemsetAsync(ssq, 0, 64 * 4, stream);
        k_stats<<<256, 256, 0, stream>>>(hout, ssum, ssq);
        k_finalize<<<1, 64, 0, stream>>>(ssum, ssq, gamma + (size_t)l * 64, beta + (size_t)l * 64, sc, sh);
        k_norm<<<(N_NODES * 16 + 255) / 256, 256, 0, stream>>>(hout, sc, sh, zz + (size_t)l * 64);
    }
    k_graph<<<(N_NODES + GNODES - 1) / GNODES, 192, 0, stream>>>(zz, batch, g);
}